// Round 1
// 4014.584 us; speedup vs baseline: 1.1301x; 1.1301x over previous
//
#include <hip/hip_runtime.h>

#define INV_SQRT2f 0.70710678118654752440f
#define INV_SQRT3f 0.57735026918962576451f

typedef __bf16 bf16x8 __attribute__((ext_vector_type(8)));
typedef float f32x4 __attribute__((ext_vector_type(4)));

__device__ __forceinline__ float silu_f(float x) { return x / (1.0f + __expf(-x)); }

enum { EPI_SILU = 0, EPI_SILU_MUL = 1, EPI_ACC = 2, EPI_RES = 3, EPI_RES2 = 4, EPI_NONE = 5 };

// ---------------------------------------------------------------------------
// Tiled bf16-MFMA GEMM: C[M,N] = epilogue(A[M,K] @ W[K,N])
// 128x128 tile, BK=32, 4 waves each computing 64x64 via 4x4 mfma_f32_16x16x32_bf16.
// A,W are f32 in global; converted to bf16 during LDS staging (fp32 accum).
// ABF16: A is already bf16 in global (row stride K, 16B-aligned rows) — staged
// directly with 16B vector loads.
// Fragment layouts (HW-verified on gfx950):
//   A: m=lane&15, k=(lane>>4)*8+j  (8 contiguous bf16 -> ds_read_b128)
//   B: n=lane&15, k=(lane>>4)*8+j  (staged transposed: Bs[n][k])
//   C/D: col=lane&15, row=(lane>>4)*4+reg
// EPI_RES/EPI_RES2 may have C == res0/res1 (in-place): each element is read
// and written by exactly one thread, and res* are never the A operand.
template <int EPI, bool CONCAT, bool ABF16 = false>
__global__ __launch_bounds__(256) void gemm_k(
    const float* A, const float* W, float* C, int M, int N, int K,
    const float* mul, const int* perm, const float* res0, const float* res1,
    float scale, const float* h_src, const int* gidx_s, const int* gidx_t,
    const float* m_src)
{
  constexpr int LSTR = 40;            // 32 + 8 pad; 80B rows: 16B-aligned, low-conflict
  __shared__ __bf16 As[128 * LSTR];
  __shared__ __bf16 Bs[128 * LSTR];
  const int tid  = threadIdx.x;
  const int lane = tid & 63;
  const int wave = tid >> 6;
  const int bm = blockIdx.x << 7;
  const int bn = blockIdx.y << 7;
  const int wm = (wave & 1) << 6;
  const int wn = (wave >> 1) << 6;
  const int fm = lane & 15;
  const int qk = (lane >> 4) << 3;

  f32x4 acc[4][4] = {};

  const int nkt = K >> 5;
  for (int kt = 0; kt < nkt; ++kt) {
    const int k0 = kt << 5;
    if constexpr (ABF16) {
      // ---- stage A tile (128x32 bf16), 2 x 16B per thread ----
      const __bf16* Ab = (const __bf16*)A;
#pragma unroll
      for (int i = 0; i < 2; ++i) {
        const int f   = tid + (i << 8);     // 0..511
        const int row = f >> 2;
        const int c8  = (f & 3) << 3;
        int gm = bm + row;
        if (gm >= M) gm = M - 1;
        const bf16x8 v = *(const bf16x8*)(Ab + (size_t)gm * K + k0 + c8);
        *(bf16x8*)&As[row * LSTR + c8] = v;
      }
    } else {
      // ---- stage A tile (128x32 f32 -> bf16), 4 float4 per thread ----
#pragma unroll
      for (int i = 0; i < 4; ++i) {
        const int f   = tid + (i << 8);
        const int row = f >> 3;
        const int c4  = (f & 7) << 2;
        int gm = bm + row;
        if (gm >= M) gm = M - 1;            // clamp; stores are guarded
        const int gk = k0 + c4;
        float4 v;
        if (CONCAT) {
          // A row = [ h[idx_s[e]] (128) | h[idx_t[e]] (128) | m_after[e] (512) ]
          const float* src;
          if (gk < 128)      src = h_src + ((size_t)gidx_s[gm] << 7) + gk;
          else if (gk < 256) src = h_src + ((size_t)gidx_t[gm] << 7) + (gk - 128);
          else               src = m_src + ((size_t)gm << 9) + (gk - 256);
          v = *(const float4*)src;
        } else {
          v = *(const float4*)(A + (size_t)gm * K + gk);
        }
        __bf16* dst = &As[row * LSTR + c4];
        dst[0] = (__bf16)v.x; dst[1] = (__bf16)v.y;
        dst[2] = (__bf16)v.z; dst[3] = (__bf16)v.w;
      }
    }
    // ---- stage B tile (32x128 f32 -> bf16, transposed into Bs[n][k]) ----
#pragma unroll
    for (int i = 0; i < 4; ++i) {
      const int f  = tid + (i << 8);
      const int kk = f >> 5;
      const int n4 = (f & 31) << 2;
      int gn = bn + n4;
      if (gn > N - 4) gn = N - 4;           // clamp (N multiple of 4); stores guarded
      const float4 v = *(const float4*)(W + (size_t)(k0 + kk) * N + gn);
      Bs[(n4 + 0) * LSTR + kk] = (__bf16)v.x;
      Bs[(n4 + 1) * LSTR + kk] = (__bf16)v.y;
      Bs[(n4 + 2) * LSTR + kk] = (__bf16)v.z;
      Bs[(n4 + 3) * LSTR + kk] = (__bf16)v.w;
    }
    __syncthreads();
    bf16x8 af[4], bfv[4];
#pragma unroll
    for (int mt = 0; mt < 4; ++mt)
      af[mt] = *(const bf16x8*)&As[(wm + mt * 16 + fm) * LSTR + qk];
#pragma unroll
    for (int nt = 0; nt < 4; ++nt)
      bfv[nt] = *(const bf16x8*)&Bs[(wn + nt * 16 + fm) * LSTR + qk];
#pragma unroll
    for (int mt = 0; mt < 4; ++mt)
#pragma unroll
      for (int nt = 0; nt < 4; ++nt)
        acc[mt][nt] = __builtin_amdgcn_mfma_f32_16x16x32_bf16(af[mt], bfv[nt], acc[mt][nt], 0, 0, 0);
    __syncthreads();
  }

  // ---- epilogue ----
#pragma unroll
  for (int mt = 0; mt < 4; ++mt) {
#pragma unroll
    for (int nt = 0; nt < 4; ++nt) {
#pragma unroll
      for (int r = 0; r < 4; ++r) {
        const int row = bm + wm + mt * 16 + ((lane >> 4) << 2) + r;
        const int col = bn + wn + nt * 16 + fm;
        if (row < M && col < N) {
          const float s = acc[mt][nt][r];
          const size_t o = (size_t)row * N + col;
          if constexpr (EPI == EPI_SILU) {
            C[o] = silu_f(s) * scale;
          } else if constexpr (EPI == EPI_SILU_MUL) {
            C[o] = silu_f(s) * mul[o];
          } else if constexpr (EPI == EPI_ACC) {
            const int rr = perm ? perm[row] : row;   // inverse-permutation scatter for [id_swap]
            C[(size_t)rr * N + col] += silu_f(s) * scale;
          } else if constexpr (EPI == EPI_RES) {
            C[o] = (res0[o] + silu_f(s)) * scale;
          } else if constexpr (EPI == EPI_RES2) {
            // (res0 + (res1 + silu(S))/sqrt2)/sqrt2
            C[o] = (res0[o] + (res1[o] + silu_f(s)) * INV_SQRT2f) * INV_SQRT2f;
          } else { // EPI_NONE
            C[o] = s * scale;
          }
        }
      }
    }
  }
}

// ---------------------------------------------------------------------------
// C[M,512] = rbf[M,16] @ W[16,512]   (memory-bound K=16 projection)
__global__ __launch_bounds__(256) void rbf_proj_k(
    const float* __restrict__ rbf, const float* __restrict__ W,
    float* __restrict__ out, int M)
{
  const int g = blockIdx.x * 256 + threadIdx.x;
  const int e = g >> 9, c = g & 511;
  if (e >= M) return;
  const float* r = rbf + (size_t)e * 16;
  float s = 0.0f;
#pragma unroll
  for (int j = 0; j < 16; ++j) s += r[j] * W[(j << 9) + c];
  out[g] = s;
}

// ---------------------------------------------------------------------------
// BI[i, 0:64] = XQE[id4_expand_intm_db[i]] * (cbf4[i] @ Wq_cbf)   (400000 rows)
__global__ __launch_bounds__(256) void quad_interm_k(
    const float* __restrict__ xqe, const float* __restrict__ cbf,
    const float* __restrict__ Wcbf, const int* __restrict__ idb,
    float* __restrict__ out)
{
  __shared__ float Ws[1024];   // 16x64
  const int t = threadIdx.x;
  for (int i = t; i < 1024; i += 256) Ws[i] = Wcbf[i];
  __syncthreads();
  const int i = blockIdx.x * 4 + (t >> 6);
  const int c = t & 63;
  const float* cb = cbf + (size_t)i * 16;
  float s = 0.0f;
#pragma unroll
  for (int j = 0; j < 16; ++j) s += cb[j] * Ws[j * 64 + c];
  out[(size_t)i * 64 + c] = xqe[(size_t)idb[i] * 64 + c] * s;
}

// ---------------------------------------------------------------------------
// Quad per-edge small contractions, 1 edge per wave, 4 edges/block.
//   val[k=16][h=lane]  gathered from BI rows (id4_expand_abd)
//   sumk[n=16][h] = sph^T val        (16x16x64 per edge)
//   r[i=32][h]    = rbfW1 sumk       (32x16x64 per edge)
// Output: R[e][h*32+i] as bf16 — matches Wq_bil's (h,i) row ordering so the
// final contraction becomes a plain GEMM (50000x2048)@(2048x32) on MFMA.
__global__ __launch_bounds__(256) void quad_r_k(
    const float* __restrict__ BI, const float* __restrict__ sph,
    const float* __restrict__ rbfW, const int* __restrict__ abd,
    __bf16* __restrict__ R)
{
  __shared__ float sp[4][256];   // [wave][k*16+n]
  __shared__ float rw[4][512];   // [wave][i*16+n]
  const int t = threadIdx.x;
  const int lane = t & 63;
  const int w = t >> 6;
  const int e = blockIdx.x * 4 + w;

  *(float4*)&sp[w][lane << 2] = *(const float4*)(sph + (size_t)e * 256 + (lane << 2));
  *(float4*)&rw[w][lane << 2] = *(const float4*)(rbfW + (size_t)e * 512 + (lane << 2));
  *(float4*)&rw[w][256 + (lane << 2)] = *(const float4*)(rbfW + (size_t)e * 512 + 256 + (lane << 2));

  float val[16];
#pragma unroll
  for (int k = 0; k < 16; ++k)
    val[k] = BI[(size_t)abd[e * 16 + k] * 64 + lane];

  __syncthreads();   // each wave reads only its own sp[w]/rw[w]; fence LDS writes

  float sumk[16] = {};
#pragma unroll
  for (int k = 0; k < 16; ++k) {
    const float v = val[k];
#pragma unroll
    for (int n = 0; n < 16; ++n) sumk[n] += sp[w][k * 16 + n] * v;
  }

#pragma unroll
  for (int ib = 0; ib < 4; ++ib) {
    bf16x8 pack;
#pragma unroll
    for (int j = 0; j < 8; ++j) {
      const int i = ib * 8 + j;
      float s = 0.0f;
#pragma unroll
      for (int n = 0; n < 16; ++n) s += rw[w][i * 16 + n] * sumk[n];
      pack[j] = (__bf16)s;
    }
    // lane h writes its 32 consecutive bf16 (64B) in 4 x 16B stores
    *(bf16x8*)(R + (size_t)e * 2048 + (lane << 5) + (ib << 3)) = pack;
  }
}

// ---------------------------------------------------------------------------
// Triplet analog: val gathered from XTE via id3_expand_ba; nSph=7, i<16.
// Output: R[e][h*16+i] bf16 — matches Wt_bil's (h,i) ordering; final is
// GEMM (50000x1024)@(1024x64).
__global__ __launch_bounds__(256) void trip_r_k(
    const float* __restrict__ XTE, const float* __restrict__ sph,
    const float* __restrict__ rbfW, const int* __restrict__ ba,
    __bf16* __restrict__ R)
{
  __shared__ float sp[4][112];   // [wave][k*7+n]
  __shared__ float rw[4][112];   // [wave][i*7+n]
  const int t = threadIdx.x;
  const int lane = t & 63;
  const int w = t >> 6;
  const int e = blockIdx.x * 4 + w;

  if (lane < 28) {
    *(float4*)&sp[w][lane << 2] = *(const float4*)(sph + (size_t)e * 112 + (lane << 2));
  } else if (lane >= 32 && lane < 60) {
    const int q = (lane - 32) << 2;
    *(float4*)&rw[w][q] = *(const float4*)(rbfW + (size_t)e * 112 + q);
  }

  float val[16];
#pragma unroll
  for (int k = 0; k < 16; ++k)
    val[k] = XTE[(size_t)ba[e * 16 + k] * 64 + lane];

  __syncthreads();

  float sumk[7] = {};
#pragma unroll
  for (int k = 0; k < 16; ++k) {
    const float v = val[k];
#pragma unroll
    for (int n = 0; n < 7; ++n) sumk[n] += sp[w][k * 7 + n] * v;
  }

#pragma unroll
  for (int ib = 0; ib < 2; ++ib) {
    bf16x8 pack;
#pragma unroll
    for (int j = 0; j < 8; ++j) {
      const int i = ib * 8 + j;
      float s = 0.0f;
#pragma unroll
      for (int n = 0; n < 7; ++n) s += rw[w][i * 7 + n] * sumk[n];
      pack[j] = (__bf16)s;
    }
    *(bf16x8*)(R + (size_t)e * 1024 + (lane << 4) + (ib << 3)) = pack;
  }
}

// ---------------------------------------------------------------------------
__global__ __launch_bounds__(256) void inv_perm_k(const int* __restrict__ p,
                                                  int* __restrict__ inv, int n)
{
  const int i = blockIdx.x * 256 + threadIdx.x;
  if (i < n) inv[p[i]] = i;
}

__global__ __launch_bounds__(256) void zero_k(float* __restrict__ p, int n)
{
  const int i = blockIdx.x * 256 + threadIdx.x;
  if (i < n) p[i] = 0.0f;
}

// segment-sum scatter: A0[idx_t[e], c] += m_after[e,c] * rh[e,c]
__global__ __launch_bounds__(256) void atom_scatter_k(
    const float* __restrict__ mafter, const float* __restrict__ rh,
    const int* __restrict__ idxt, float* __restrict__ A0, int nE)
{
  const int g = blockIdx.x * 256 + threadIdx.x;
  const int e = g >> 9, c = g & 511;
  if (e >= nE) return;
  const size_t o = (size_t)e * 512 + c;
  atomicAdd(&A0[(size_t)idxt[e] * 512 + c], mafter[o] * rh[o]);
}

__global__ __launch_bounds__(256) void hout_k(const float* __restrict__ h,
                                              const float* __restrict__ xa,
                                              float* __restrict__ out, int n)
{
  const int i = blockIdx.x * 256 + threadIdx.x;
  if (i < n) out[i] = (h[i] + xa[i]) * INV_SQRT2f;
}

// ---------------------------------------------------------------------------
extern "C" void kernel_launch(void* const* d_in, const int* in_sizes, int n_in,
                              void* d_out, int out_size, void* d_ws, size_t ws_size,
                              hipStream_t stream) {
  (void)in_sizes; (void)n_in; (void)out_size; (void)ws_size;
  const float* h        = (const float*)d_in[0];
  const float* m        = (const float*)d_in[1];
  const float* rbf4     = (const float*)d_in[2];
  const float* cbf4     = (const float*)d_in[3];
  const float* rbfW4    = (const float*)d_in[4];
  const float* sph4     = (const float*)d_in[5];
  const float* rbf3     = (const float*)d_in[6];
  const float* rbfW3    = (const float*)d_in[7];
  const float* sph3     = (const float*)d_in[8];
  const float* rbf_h    = (const float*)d_in[9];
  const float* W_dense  = (const float*)d_in[10];
  const float* Wq_db    = (const float*)d_in[11];
  const float* Wq_rbf   = (const float*)d_in[12];
  const float* Wq_cbf   = (const float*)d_in[13];
  const float* Wq_bil   = (const float*)d_in[14];
  const float* Wq_down  = (const float*)d_in[15];
  const float* Wq_up_ca = (const float*)d_in[16];
  const float* Wq_up_ac = (const float*)d_in[17];
  const float* Wt_ba    = (const float*)d_in[18];
  const float* Wt_rbf   = (const float*)d_in[19];
  const float* Wt_bil   = (const float*)d_in[20];
  const float* Wt_down  = (const float*)d_in[21];
  const float* Wt_up_ca = (const float*)d_in[22];
  const float* Wt_up_ac = (const float*)d_in[23];
  const float* W_before = (const float*)d_in[24];
  const float* W_after  = (const float*)d_in[25];
  const float* W_au_rbf = (const float*)d_in[26];
  const float* W_au_dns = (const float*)d_in[27];
  const float* W_au_res = (const float*)d_in[28];
  const float* W_concat = (const float*)d_in[29];
  const float* W_resm   = (const float*)d_in[30];
  const int* id_swap    = (const int*)d_in[32];
  const int* id4_db     = (const int*)d_in[34];
  const int* id4_abd    = (const int*)d_in[35];
  const int* id3_ba     = (const int*)d_in[37];
  const int* idx_s      = (const int*)d_in[39];
  const int* idx_t      = (const int*)d_in[40];

  // ---- workspace layout (floats), liveness-overlapped; total ~224 MiB ----
  // B0, B1: 50000x512 ping-pong.  XQE/XTE alias B1's later life.
  // RQ (bf16, 50000x2048 = 200MB) spans exactly [B0,B1] while both are dead
  // (after quad_interm consumes XQE, before trip branch reuses B1).
  // RT (bf16, 50000x1024 = 100MB) spans exactly B0 while XTE (B1) is read.
  // R region: XQB/XTB early, A0/A1/A2 (atom phase) later.
  // BI (400000x64) and the m_after "X" buffer live in d_out's m region.
  float* w = (float*)d_ws;
  const size_t S = 25600000;                 // 50000*512
  float* B0  = w;
  float* B1  = w + S;
  float* XQE = B1;                           // 50000*64, alias (B1 free at that point)
  float* XTE = B1;                           // 50000*64, alias
  __bf16* RQ = (__bf16*)w;                   // 50000*2048 bf16 = B0+B1 exactly
  __bf16* RT = (__bf16*)w;                   // 50000*1024 bf16 = B0 exactly
  float* R   = w + 2 * S;                    // 4.8M floats
  float* XQB = R;                            // 50000*32 = 1.6M
  float* XTB = R + 1600000;                  // 50000*64 = 3.2M
  float* A0  = R;                            // 5000*512 = 2.56M (after XQB/XTB dead)
  float* A1  = R + 2560000;                  // 5000*128
  float* A2  = R + 3200000;                  // 5000*128
  int*   INV = (int*)(R + 4800000);          // 50000 ints

  float* out_h = (float*)d_out;              // 5000*128
  float* out_m = out_h + 640000;             // 50000*512 — doubles as BI, then X (m_after)
  float* BI    = out_m;                      // 400000*64 = 25.6M exactly

  const float s23 = INV_SQRT2f * INV_SQRT3f;
  const dim3 blk(256);
  const dim3 gFull(391, 4), gN64(391, 1), gBil(391, 1), gAtom(40, 1);
#define NUL9 nullptr, nullptr, nullptr, nullptr
#define TAIL4 nullptr, nullptr, nullptr, nullptr

  inv_perm_k<<<196, blk, 0, stream>>>(id_swap, INV, 50000);

  // ---- quadruplet branch ----
  rbf_proj_k<<<100000, blk, 0, stream>>>(rbf4, Wq_rbf, B1, 50000);
  gemm_k<EPI_SILU_MUL, false><<<gFull, blk, 0, stream>>>(m, Wq_db, B0, 50000, 512, 512,
      B1, nullptr, nullptr, nullptr, 1.0f, TAIL4);
  gemm_k<EPI_SILU, false><<<gN64, blk, 0, stream>>>(B0, Wq_down, XQE, 50000, 64, 512,
      NUL9, 1.0f, TAIL4);
  quad_interm_k<<<100000, blk, 0, stream>>>(XQE, cbf4, Wq_cbf, id4_db, BI);
  quad_r_k<<<12500, blk, 0, stream>>>(BI, sph4, rbfW4, id4_abd, RQ);
  gemm_k<EPI_NONE, false, true><<<gBil, blk, 0, stream>>>((const float*)RQ, Wq_bil, XQB,
      50000, 32, 2048, NUL9, 1.0f, TAIL4);

  // ---- triplet branch ----
  rbf_proj_k<<<100000, blk, 0, stream>>>(rbf3, Wt_rbf, B1, 50000);
  gemm_k<EPI_SILU_MUL, false><<<gFull, blk, 0, stream>>>(m, Wt_ba, B0, 50000, 512, 512,
      B1, nullptr, nullptr, nullptr, 1.0f, TAIL4);
  gemm_k<EPI_SILU, false><<<gN64, blk, 0, stream>>>(B0, Wt_down, XTE, 50000, 64, 512,
      NUL9, 1.0f, TAIL4);
  trip_r_k<<<12500, blk, 0, stream>>>(XTE, sph3, rbfW3, id3_ba, RT);
  gemm_k<EPI_NONE, false, true><<<gBil, blk, 0, stream>>>((const float*)RT, Wt_bil, XTB,
      50000, 64, 1024, NUL9, 1.0f, TAIL4);

  // ---- merge: x = (x_ca + x4 + x3)/sqrt3, up-projections accumulate in epilogue ----
  gemm_k<EPI_SILU, false><<<gFull, blk, 0, stream>>>(m, W_dense, B0, 50000, 512, 512,
      NUL9, INV_SQRT3f, TAIL4);
  gemm_k<EPI_ACC, false><<<gFull, blk, 0, stream>>>(XQB, Wq_up_ca, B0, 50000, 512, 32,
      nullptr, nullptr, nullptr, nullptr, s23, TAIL4);
  gemm_k<EPI_ACC, false><<<gFull, blk, 0, stream>>>(XQB, Wq_up_ac, B0, 50000, 512, 32,
      nullptr, INV, nullptr, nullptr, s23, TAIL4);
  gemm_k<EPI_ACC, false><<<gFull, blk, 0, stream>>>(XTB, Wt_up_ca, B0, 50000, 512, 64,
      nullptr, nullptr, nullptr, nullptr, s23, TAIL4);
  gemm_k<EPI_ACC, false><<<gFull, blk, 0, stream>>>(XTB, Wt_up_ac, B0, 50000, 512, 64,
      nullptr, INV, nullptr, nullptr, s23, TAIL4);

  // ---- W_before (1 layer) + m add -> X := out_m; then W_after (2 layers, in place) ----
  gemm_k<EPI_SILU, false><<<gFull, blk, 0, stream>>>(B0, W_before, B1, 50000, 512, 512,
      NUL9, 1.0f, TAIL4);
  gemm_k<EPI_RES2, false><<<gFull, blk, 0, stream>>>(B1, W_before + 262144, out_m, 50000, 512, 512,
      nullptr, nullptr, m, B0, 1.0f, TAIL4);
  gemm_k<EPI_SILU, false><<<gFull, blk, 0, stream>>>(out_m, W_after, B1, 50000, 512, 512,
      NUL9, 1.0f, TAIL4);
  gemm_k<EPI_RES, false><<<gFull, blk, 0, stream>>>(B1, W_after + 262144, out_m, 50000, 512, 512,
      nullptr, nullptr, out_m, nullptr, INV_SQRT2f, TAIL4);
  gemm_k<EPI_SILU, false><<<gFull, blk, 0, stream>>>(out_m, W_after + 524288, B1, 50000, 512, 512,
      NUL9, 1.0f, TAIL4);
  gemm_k<EPI_RES, false><<<gFull, blk, 0, stream>>>(B1, W_after + 786432, out_m, 50000, 512, 512,
      nullptr, nullptr, out_m, nullptr, INV_SQRT2f, TAIL4);
  // out_m = m_after

  // ---- atom update ----
  rbf_proj_k<<<100000, blk, 0, stream>>>(rbf_h, W_au_rbf, B1, 50000);
  zero_k<<<10000, blk, 0, stream>>>(A0, 2560000);
  atom_scatter_k<<<100000, blk, 0, stream>>>(out_m, B1, idx_t, A0, 50000);
  gemm_k<EPI_SILU, false><<<gAtom, blk, 0, stream>>>(A0, W_au_dns, A1, 5000, 128, 512,
      NUL9, 1.0f, TAIL4);
  for (int l = 0; l < 3; ++l) {
    gemm_k<EPI_SILU, false><<<gAtom, blk, 0, stream>>>(A1, W_au_res + (size_t)(2 * l) * 16384,
        A2, 5000, 128, 128, NUL9, 1.0f, TAIL4);
    gemm_k<EPI_RES, false><<<gAtom, blk, 0, stream>>>(A2, W_au_res + (size_t)(2 * l + 1) * 16384,
        A1, 5000, 128, 128, nullptr, nullptr, A1, nullptr, INV_SQRT2f, TAIL4);
  }
  hout_k<<<2500, blk, 0, stream>>>(h, A1, out_h, 640000);

  // ---- concat re-embedding + W_resm, final m write (in place on out_m) ----
  gemm_k<EPI_SILU, true><<<gFull, blk, 0, stream>>>(nullptr, W_concat, B0, 50000, 512, 768,
      nullptr, nullptr, nullptr, nullptr, 1.0f, out_h, idx_s, idx_t, out_m);
  gemm_k<EPI_SILU, false><<<gFull, blk, 0, stream>>>(B0, W_resm, B1, 50000, 512, 512,
      NUL9, 1.0f, TAIL4);
  gemm_k<EPI_RES2, false><<<gFull, blk, 0, stream>>>(B1, W_resm + 262144, out_m, 50000, 512, 512,
      nullptr, nullptr, out_m, B0, 1.0f, TAIL4);
#undef NUL9
#undef TAIL4
}

// Round 3
// 3202.491 us; speedup vs baseline: 1.4167x; 1.2536x over previous
//
#include <hip/hip_runtime.h>

#define INV_SQRT2f 0.70710678118654752440f
#define INV_SQRT3f 0.57735026918962576451f

typedef __bf16 bf16x8 __attribute__((ext_vector_type(8)));
typedef float f32x4 __attribute__((ext_vector_type(4)));

__device__ __forceinline__ float silu_f(float x) { return x / (1.0f + __expf(-x)); }

enum { EPI_SILU = 0, EPI_SILU_MUL = 1, EPI_ACC = 2, EPI_RES = 3, EPI_RES2 = 4, EPI_NONE = 5 };

// ---------------------------------------------------------------------------
// Weight pre-transpose/convert: Wt[n][k] bf16  <-  W[k][n] f32.
// Same f32->bf16 rounding the GEMM staging used to do, done once. B-staging
// then reads bf16 K-rows contiguously (16B/lane) and writes LDS with
// conflict-free ds_write_b128, eliminating the 16-way-conflict scalar
// transpose writes (7.9e7 conflict cycles/dispatch measured in round 1).
// Weights are carved into three liveness windows (Z1/Z5/Z3, see launch) so
// the total workspace footprint is UNCHANGED from the proven round-1 layout.
struct WT { const float* src; __bf16* dst; int K; int N; };
struct WTBatch { WT d[18]; };

__global__ __launch_bounds__(256) void wconv_k(WTBatch b)
{
  __shared__ float t[64][65];
  const WT w = b.d[blockIdx.z];
  const int k0 = blockIdx.x << 6, n0 = blockIdx.y << 6;
  if (k0 >= w.K || n0 >= w.N) return;
  const int tx = threadIdx.x & 63, ty = threadIdx.x >> 6;
#pragma unroll
  for (int i = 0; i < 16; ++i) {
    const int k = (i << 2) + ty;
    const int gk = k0 + k, gn = n0 + tx;
    t[k][tx] = (gk < w.K && gn < w.N) ? w.src[(size_t)gk * w.N + gn] : 0.0f;
  }
  __syncthreads();
#pragma unroll
  for (int i = 0; i < 16; ++i) {
    const int n = (i << 2) + ty;
    const int gn = n0 + n, gk = k0 + tx;
    if (gn < w.N && gk < w.K) w.dst[(size_t)gn * w.K + gk] = (__bf16)t[tx][n];
  }
}

// ---------------------------------------------------------------------------
// Tiled bf16-MFMA GEMM: C[M,N] = epilogue(A[M,K] @ W[K,N])
// 128x128 tile, BK=32, 4 waves each computing 64x64 via 4x4 mfma_f32_16x16x32_bf16.
// A is f32 in global (converted to bf16 during LDS staging) unless ABF16.
// W is PRE-TRANSPOSED bf16 [N][K] (see wconv_k).
// Fragment layouts (HW-verified on gfx950):
//   A: m=lane&15, k=(lane>>4)*8+j  (8 contiguous bf16 -> ds_read_b128)
//   B: n=lane&15, k=(lane>>4)*8+j  (Bs[n][k])
//   C/D: col=lane&15, row=(lane>>4)*4+reg
// EPI_RES/EPI_RES2 may have C == res0/res1 (in-place): each element is read
// and written by exactly one thread, and res* are never the A operand.
template <int EPI, bool CONCAT, bool ABF16 = false>
__global__ __launch_bounds__(256) void gemm_k(
    const float* A, const __bf16* W, float* C, int M, int N, int K,
    const float* mul, const int* perm, const float* res0, const float* res1,
    float scale, const float* h_src, const int* gidx_s, const int* gidx_t,
    const float* m_src)
{
  constexpr int LSTR = 40;            // 32 + 8 pad; 80B rows: 16B-aligned, low-conflict
  __shared__ __bf16 As[128 * LSTR];
  __shared__ __bf16 Bs[128 * LSTR];
  const int tid  = threadIdx.x;
  const int lane = tid & 63;
  const int wave = tid >> 6;
  const int bm = blockIdx.x << 7;
  const int bn = blockIdx.y << 7;
  const int wm = (wave & 1) << 6;
  const int wn = (wave >> 1) << 6;
  const int fm = lane & 15;
  const int qk = (lane >> 4) << 3;

  f32x4 acc[4][4] = {};

  const int nkt = K >> 5;
  for (int kt = 0; kt < nkt; ++kt) {
    const int k0 = kt << 5;
    if constexpr (ABF16) {
      // ---- stage A tile (128x32 bf16), 2 x 16B per thread ----
      const __bf16* Ab = (const __bf16*)A;
#pragma unroll
      for (int i = 0; i < 2; ++i) {
        const int f   = tid + (i << 8);     // 0..511
        const int row = f >> 2;
        const int c8  = (f & 3) << 3;
        int gm = bm + row;
        if (gm >= M) gm = M - 1;
        const bf16x8 v = *(const bf16x8*)(Ab + (size_t)gm * K + k0 + c8);
        *(bf16x8*)&As[row * LSTR + c8] = v;
      }
    } else {
      // ---- stage A tile (128x32 f32 -> bf16), 4 float4 per thread ----
#pragma unroll
      for (int i = 0; i < 4; ++i) {
        const int f   = tid + (i << 8);
        const int row = f >> 3;
        const int c4  = (f & 7) << 2;
        int gm = bm + row;
        if (gm >= M) gm = M - 1;            // clamp; stores are guarded
        const int gk = k0 + c4;
        float4 v;
        if (CONCAT) {
          // A row = [ h[idx_s[e]] (128) | h[idx_t[e]] (128) | m_after[e] (512) ]
          const float* src;
          if (gk < 128)      src = h_src + ((size_t)gidx_s[gm] << 7) + gk;
          else if (gk < 256) src = h_src + ((size_t)gidx_t[gm] << 7) + (gk - 128);
          else               src = m_src + ((size_t)gm << 9) + (gk - 256);
          v = *(const float4*)src;
        } else {
          v = *(const float4*)(A + (size_t)gm * K + gk);
        }
        __bf16* dst = &As[row * LSTR + c4];
        dst[0] = (__bf16)v.x; dst[1] = (__bf16)v.y;
        dst[2] = (__bf16)v.z; dst[3] = (__bf16)v.w;
      }
    }
    // ---- stage B tile (128n x 32k) from pre-transposed bf16 W[n][k] ----
#pragma unroll
    for (int i = 0; i < 2; ++i) {
      const int f  = tid + (i << 8);        // 0..511
      const int n  = f >> 2;
      const int c8 = (f & 3) << 3;
      int gn = bn + n;
      if (gn >= N) gn = N - 1;              // clamp; epilogue guards col<N
      const bf16x8 v = *(const bf16x8*)(W + (size_t)gn * K + k0 + c8);
      *(bf16x8*)&Bs[n * LSTR + c8] = v;
    }
    __syncthreads();
    bf16x8 af[4], bfv[4];
#pragma unroll
    for (int mt = 0; mt < 4; ++mt)
      af[mt] = *(const bf16x8*)&As[(wm + mt * 16 + fm) * LSTR + qk];
#pragma unroll
    for (int nt = 0; nt < 4; ++nt)
      bfv[nt] = *(const bf16x8*)&Bs[(wn + nt * 16 + fm) * LSTR + qk];
#pragma unroll
    for (int mt = 0; mt < 4; ++mt)
#pragma unroll
      for (int nt = 0; nt < 4; ++nt)
        acc[mt][nt] = __builtin_amdgcn_mfma_f32_16x16x32_bf16(af[mt], bfv[nt], acc[mt][nt], 0, 0, 0);
    __syncthreads();
  }

  // ---- epilogue ----
#pragma unroll
  for (int mt = 0; mt < 4; ++mt) {
#pragma unroll
    for (int nt = 0; nt < 4; ++nt) {
#pragma unroll
      for (int r = 0; r < 4; ++r) {
        const int row = bm + wm + mt * 16 + ((lane >> 4) << 2) + r;
        const int col = bn + wn + nt * 16 + fm;
        if (row < M && col < N) {
          const float s = acc[mt][nt][r];
          const size_t o = (size_t)row * N + col;
          if constexpr (EPI == EPI_SILU) {
            C[o] = silu_f(s) * scale;
          } else if constexpr (EPI == EPI_SILU_MUL) {
            C[o] = silu_f(s) * mul[o];
          } else if constexpr (EPI == EPI_ACC) {
            const int rr = perm ? perm[row] : row;   // inverse-permutation scatter for [id_swap]
            C[(size_t)rr * N + col] += silu_f(s) * scale;
          } else if constexpr (EPI == EPI_RES) {
            C[o] = (res0[o] + silu_f(s)) * scale;
          } else if constexpr (EPI == EPI_RES2) {
            // (res0 + (res1 + silu(S))/sqrt2)/sqrt2
            C[o] = (res0[o] + (res1[o] + silu_f(s)) * INV_SQRT2f) * INV_SQRT2f;
          } else { // EPI_NONE
            C[o] = s * scale;
          }
        }
      }
    }
  }
}

// ---------------------------------------------------------------------------
// C[M,512] = rbf[M,16] @ W[16,512]   (memory-bound K=16 projection)
__global__ __launch_bounds__(256) void rbf_proj_k(
    const float* __restrict__ rbf, const float* __restrict__ W,
    float* __restrict__ out, int M)
{
  const int g = blockIdx.x * 256 + threadIdx.x;
  const int e = g >> 9, c = g & 511;
  if (e >= M) return;
  const float* r = rbf + (size_t)e * 16;
  float s = 0.0f;
#pragma unroll
  for (int j = 0; j < 16; ++j) s += r[j] * W[(j << 9) + c];
  out[g] = s;
}

// ---------------------------------------------------------------------------
// BI[i, 0:64] = XQE[id4_expand_intm_db[i]] * (cbf4[i] @ Wq_cbf)   (400000 rows)
__global__ __launch_bounds__(256) void quad_interm_k(
    const float* __restrict__ xqe, const float* __restrict__ cbf,
    const float* __restrict__ Wcbf, const int* __restrict__ idb,
    float* __restrict__ out)
{
  __shared__ float Ws[1024];   // 16x64
  const int t = threadIdx.x;
  for (int i = t; i < 1024; i += 256) Ws[i] = Wcbf[i];
  __syncthreads();
  const int i = blockIdx.x * 4 + (t >> 6);
  const int c = t & 63;
  const float* cb = cbf + (size_t)i * 16;
  float s = 0.0f;
#pragma unroll
  for (int j = 0; j < 16; ++j) s += cb[j] * Ws[j * 64 + c];
  out[(size_t)i * 64 + c] = xqe[(size_t)idb[i] * 64 + c] * s;
}

// ---------------------------------------------------------------------------
// Quad per-edge small contractions, 1 edge per wave, 4 edges/block.
//   val[k=16][h=lane]  gathered from BI rows (id4_expand_abd)
//   sumk[n=16][h] = sph^T val        (16x16x64 per edge)
//   r[i=32][h]    = rbfW1 sumk       (32x16x64 per edge)
// Output: R[e][h*32+i] as bf16 — matches Wq_bil's (h,i) row ordering so the
// final contraction becomes a plain GEMM (50000x2048)@(2048x32) on MFMA.
__global__ __launch_bounds__(256) void quad_r_k(
    const float* __restrict__ BI, const float* __restrict__ sph,
    const float* __restrict__ rbfW, const int* __restrict__ abd,
    __bf16* __restrict__ R)
{
  __shared__ float sp[4][256];   // [wave][k*16+n]
  __shared__ float rw[4][512];   // [wave][i*16+n]
  const int t = threadIdx.x;
  const int lane = t & 63;
  const int w = t >> 6;
  const int e = blockIdx.x * 4 + w;

  *(float4*)&sp[w][lane << 2] = *(const float4*)(sph + (size_t)e * 256 + (lane << 2));
  *(float4*)&rw[w][lane << 2] = *(const float4*)(rbfW + (size_t)e * 512 + (lane << 2));
  *(float4*)&rw[w][256 + (lane << 2)] = *(const float4*)(rbfW + (size_t)e * 512 + 256 + (lane << 2));

  float val[16];
#pragma unroll
  for (int k = 0; k < 16; ++k)
    val[k] = BI[(size_t)abd[e * 16 + k] * 64 + lane];

  __syncthreads();   // each wave reads only its own sp[w]/rw[w]; fence LDS writes

  float sumk[16] = {};
#pragma unroll
  for (int k = 0; k < 16; ++k) {
    const float v = val[k];
#pragma unroll
    for (int n = 0; n < 16; ++n) sumk[n] += sp[w][k * 16 + n] * v;
  }

#pragma unroll
  for (int ib = 0; ib < 4; ++ib) {
    bf16x8 pack;
#pragma unroll
    for (int j = 0; j < 8; ++j) {
      const int i = ib * 8 + j;
      float s = 0.0f;
#pragma unroll
      for (int n = 0; n < 16; ++n) s += rw[w][i * 16 + n] * sumk[n];
      pack[j] = (__bf16)s;
    }
    // lane h writes its 32 consecutive bf16 (64B) in 4 x 16B stores
    *(bf16x8*)(R + (size_t)e * 2048 + (lane << 5) + (ib << 3)) = pack;
  }
}

// ---------------------------------------------------------------------------
// Triplet analog: val gathered from XTE via id3_expand_ba; nSph=7, i<16.
// Output: R[e][h*16+i] bf16 — matches Wt_bil's (h,i) ordering; final is
// GEMM (50000x1024)@(1024x64).
__global__ __launch_bounds__(256) void trip_r_k(
    const float* __restrict__ XTE, const float* __restrict__ sph,
    const float* __restrict__ rbfW, const int* __restrict__ ba,
    __bf16* __restrict__ R)
{
  __shared__ float sp[4][112];   // [wave][k*7+n]
  __shared__ float rw[4][112];   // [wave][i*7+n]
  const int t = threadIdx.x;
  const int lane = t & 63;
  const int w = t >> 6;
  const int e = blockIdx.x * 4 + w;

  if (lane < 28) {
    *(float4*)&sp[w][lane << 2] = *(const float4*)(sph + (size_t)e * 112 + (lane << 2));
  } else if (lane >= 32 && lane < 60) {
    const int q = (lane - 32) << 2;
    *(float4*)&rw[w][q] = *(const float4*)(rbfW + (size_t)e * 112 + q);
  }

  float val[16];
#pragma unroll
  for (int k = 0; k < 16; ++k)
    val[k] = XTE[(size_t)ba[e * 16 + k] * 64 + lane];

  __syncthreads();

  float sumk[7] = {};
#pragma unroll
  for (int k = 0; k < 16; ++k) {
    const float v = val[k];
#pragma unroll
    for (int n = 0; n < 7; ++n) sumk[n] += sp[w][k * 7 + n] * v;
  }

#pragma unroll
  for (int ib = 0; ib < 2; ++ib) {
    bf16x8 pack;
#pragma unroll
    for (int j = 0; j < 8; ++j) {
      const int i = ib * 8 + j;
      float s = 0.0f;
#pragma unroll
      for (int n = 0; n < 7; ++n) s += rw[w][i * 7 + n] * sumk[n];
      pack[j] = (__bf16)s;
    }
    *(bf16x8*)(R + (size_t)e * 1024 + (lane << 4) + (ib << 3)) = pack;
  }
}

// ---------------------------------------------------------------------------
__global__ __launch_bounds__(256) void inv_perm_k(const int* __restrict__ p,
                                                  int* __restrict__ inv, int n)
{
  const int i = blockIdx.x * 256 + threadIdx.x;
  if (i < n) inv[p[i]] = i;
}

__global__ __launch_bounds__(256) void zero_k(float* __restrict__ p, int n)
{
  const int i = blockIdx.x * 256 + threadIdx.x;
  if (i < n) p[i] = 0.0f;
}

// segment-sum scatter: A0[idx_t[e], c] += m_after[e,c] * rh[e,c]
__global__ __launch_bounds__(256) void atom_scatter_k(
    const float* __restrict__ mafter, const float* __restrict__ rh,
    const int* __restrict__ idxt, float* __restrict__ A0, int nE)
{
  const int g = blockIdx.x * 256 + threadIdx.x;
  const int e = g >> 9, c = g & 511;
  if (e >= nE) return;
  const size_t o = (size_t)e * 512 + c;
  atomicAdd(&A0[(size_t)idxt[e] * 512 + c], mafter[o] * rh[o]);
}

__global__ __launch_bounds__(256) void hout_k(const float* __restrict__ h,
                                              const float* __restrict__ xa,
                                              float* __restrict__ out, int n)
{
  const int i = blockIdx.x * 256 + threadIdx.x;
  if (i < n) out[i] = (h[i] + xa[i]) * INV_SQRT2f;
}

// ---------------------------------------------------------------------------
extern "C" void kernel_launch(void* const* d_in, const int* in_sizes, int n_in,
                              void* d_out, int out_size, void* d_ws, size_t ws_size,
                              hipStream_t stream) {
  (void)in_sizes; (void)n_in; (void)out_size; (void)ws_size;
  const float* h        = (const float*)d_in[0];
  const float* m        = (const float*)d_in[1];
  const float* rbf4     = (const float*)d_in[2];
  const float* cbf4     = (const float*)d_in[3];
  const float* rbfW4    = (const float*)d_in[4];
  const float* sph4     = (const float*)d_in[5];
  const float* rbf3     = (const float*)d_in[6];
  const float* rbfW3    = (const float*)d_in[7];
  const float* sph3     = (const float*)d_in[8];
  const float* rbf_h    = (const float*)d_in[9];
  const float* W_dense  = (const float*)d_in[10];
  const float* Wq_db    = (const float*)d_in[11];
  const float* Wq_rbf   = (const float*)d_in[12];
  const float* Wq_cbf   = (const float*)d_in[13];
  const float* Wq_bil   = (const float*)d_in[14];
  const float* Wq_down  = (const float*)d_in[15];
  const float* Wq_up_ca = (const float*)d_in[16];
  const float* Wq_up_ac = (const float*)d_in[17];
  const float* Wt_ba    = (const float*)d_in[18];
  const float* Wt_rbf   = (const float*)d_in[19];
  const float* Wt_bil   = (const float*)d_in[20];
  const float* Wt_down  = (const float*)d_in[21];
  const float* Wt_up_ca = (const float*)d_in[22];
  const float* Wt_up_ac = (const float*)d_in[23];
  const float* W_before = (const float*)d_in[24];
  const float* W_after  = (const float*)d_in[25];
  const float* W_au_rbf = (const float*)d_in[26];
  const float* W_au_dns = (const float*)d_in[27];
  const float* W_au_res = (const float*)d_in[28];
  const float* W_concat = (const float*)d_in[29];
  const float* W_resm   = (const float*)d_in[30];
  const int* id_swap    = (const int*)d_in[32];
  const int* id4_db     = (const int*)d_in[34];
  const int* id4_abd    = (const int*)d_in[35];
  const int* id3_ba     = (const int*)d_in[37];
  const int* idx_s      = (const int*)d_in[39];
  const int* idx_t      = (const int*)d_in[40];

  // ---- workspace layout (floats), liveness-overlapped — footprint UNCHANGED
  //      from the proven round-1 layout (max offset R+4,850,000 floats) ----
  // B0, B1: 50000x512 ping-pong.  XQE/XTE alias B1's later life.
  // RQ (bf16) spans exactly [B0,B1]; RT spans exactly B0.
  // R region: XQB/XTB early, A0/A1/A2 (atom phase) later; INV at R+4.8M.
  // BI (400000x64) and the m_after "X" buffer live in d_out's m region.
  //
  // bf16 transposed weights live in three liveness windows (NO new memory):
  //  Z1 = out_h (d_out, 1,280,000 bf16 cap): free until hout_k. Holds all
  //       weights used before the atom res-stack ends (batch 1, t=0).
  //  Z5 = [R+3.84M, R+4.8M) (XTB tail, 1,920,000 bf16 cap): free after the
  //       last up_ac GEMM. Holds before0/1 + after0..3 (batch 2).
  //  Z3 = [R, ...) (A0 region, dead after A0->A1 GEMM): holds concat +
  //       resm0/1 (batch 3, converted after hout_k).
  float* w = (float*)d_ws;
  const size_t S = 25600000;                 // 50000*512
  float* B0  = w;
  float* B1  = w + S;
  float* XQE = B1;                           // 50000*64, alias (B1 free at that point)
  float* XTE = B1;                           // 50000*64, alias
  __bf16* RQ = (__bf16*)w;                   // 50000*2048 bf16 = B0+B1 exactly
  __bf16* RT = (__bf16*)w;                   // 50000*1024 bf16 = B0 exactly
  float* R   = w + 2 * S;                    // 4.8M floats
  float* XQB = R;                            // 50000*32 = 1.6M
  float* XTB = R + 1600000;                  // 50000*64 = 3.2M
  float* A0  = R;                            // 5000*512 = 2.56M (after XQB/XTB dead)
  float* A1  = R + 2560000;                  // 5000*128
  float* A2  = R + 3200000;                  // 5000*128
  int*   INV = (int*)(R + 4800000);          // 50000 ints (untouched by weights!)

  float* out_h = (float*)d_out;              // 5000*128
  float* out_m = out_h + 640000;             // 50000*512 — doubles as BI, then X (m_after)
  float* BI    = out_m;                      // 400000*64 = 25.6M exactly

  // ---- carve bf16 weight zones ----
  WTBatch b1{}, b2{}, b3{};
  int n1 = 0, n2 = 0, n3 = 0;
  __bf16* z1p = (__bf16*)out_h;              // cap 1,280,000 bf16
  __bf16* z5p = (__bf16*)(R + 3840000);      // cap 1,920,000 bf16
  __bf16* z3p = (__bf16*)R;                  // cap 3,200,000 bf16
  auto cv1 = [&](const float* s, int K, int N) { __bf16* d = z1p; z1p += (size_t)K * N; b1.d[n1++] = WT{s, d, K, N}; return d; };
  auto cv2 = [&](const float* s, int K, int N) { __bf16* d = z5p; z5p += (size_t)K * N; b2.d[n2++] = WT{s, d, K, N}; return d; };
  auto cv3 = [&](const float* s, int K, int N) { __bf16* d = z3p; z3p += (size_t)K * N; b3.d[n3++] = WT{s, d, K, N}; return d; };

  // Z1 (used d3..pre-hout): total 1,245,184 bf16 <= 1,280,000 cap
  __bf16* Wb_q_db    = cv1(Wq_db,    512, 512);
  __bf16* Wb_q_down  = cv1(Wq_down,  512,  64);
  __bf16* Wb_q_bil   = cv1(Wq_bil,  2048,  32);
  __bf16* Wb_t_ba    = cv1(Wt_ba,    512, 512);
  __bf16* Wb_t_down  = cv1(Wt_down,  512,  64);
  __bf16* Wb_t_bil   = cv1(Wt_bil,  1024,  64);
  __bf16* Wb_dense   = cv1(W_dense,  512, 512);
  __bf16* Wb_q_up_ca = cv1(Wq_up_ca,  32, 512);
  __bf16* Wb_q_up_ac = cv1(Wq_up_ac,  32, 512);
  __bf16* Wb_t_up_ca = cv1(Wt_up_ca,  64, 512);
  __bf16* Wb_t_up_ac = cv1(Wt_up_ac,  64, 512);
  __bf16* Wb_au_dns  = cv1(W_au_dns, 512, 128);
  __bf16* Wb_au_res[6];
  for (int l = 0; l < 6; ++l) Wb_au_res[l] = cv1(W_au_res + (size_t)l * 16384, 128, 128);
  // Z5 (used after up_ac GEMMs): 1,572,864 bf16 <= 1,920,000 cap
  __bf16* Wb_before0 = cv2(W_before,          512, 512);
  __bf16* Wb_before1 = cv2(W_before + 262144, 512, 512);
  __bf16* Wb_after[4];
  for (int l = 0; l < 4; ++l) Wb_after[l] = cv2(W_after + (size_t)l * 262144, 512, 512);
  // Z3 (used after hout): 917,504 bf16 <= 3,200,000 cap
  __bf16* Wb_concat  = cv3(W_concat,        768, 512);
  __bf16* Wb_resm0   = cv3(W_resm,          512, 512);
  __bf16* Wb_resm1   = cv3(W_resm + 262144, 512, 512);

  const float s23 = INV_SQRT2f * INV_SQRT3f;
  const dim3 blk(256);
  const dim3 gFull(391, 4), gN64(391, 1), gBil(391, 1), gAtom(40, 1);
#define NUL9 nullptr, nullptr, nullptr, nullptr
#define TAIL4 nullptr, nullptr, nullptr, nullptr

  wconv_k<<<dim3(32, 8, n1), blk, 0, stream>>>(b1);   // max K=2048 (q_bil)
  inv_perm_k<<<196, blk, 0, stream>>>(id_swap, INV, 50000);

  // ---- quadruplet branch ----
  rbf_proj_k<<<100000, blk, 0, stream>>>(rbf4, Wq_rbf, B1, 50000);
  gemm_k<EPI_SILU_MUL, false><<<gFull, blk, 0, stream>>>(m, Wb_q_db, B0, 50000, 512, 512,
      B1, nullptr, nullptr, nullptr, 1.0f, TAIL4);
  gemm_k<EPI_SILU, false><<<gN64, blk, 0, stream>>>(B0, Wb_q_down, XQE, 50000, 64, 512,
      NUL9, 1.0f, TAIL4);
  quad_interm_k<<<100000, blk, 0, stream>>>(XQE, cbf4, Wq_cbf, id4_db, BI);
  quad_r_k<<<12500, blk, 0, stream>>>(BI, sph4, rbfW4, id4_abd, RQ);
  gemm_k<EPI_NONE, false, true><<<gBil, blk, 0, stream>>>((const float*)RQ, Wb_q_bil, XQB,
      50000, 32, 2048, NUL9, 1.0f, TAIL4);

  // ---- triplet branch ----
  rbf_proj_k<<<100000, blk, 0, stream>>>(rbf3, Wt_rbf, B1, 50000);
  gemm_k<EPI_SILU_MUL, false><<<gFull, blk, 0, stream>>>(m, Wb_t_ba, B0, 50000, 512, 512,
      B1, nullptr, nullptr, nullptr, 1.0f, TAIL4);
  gemm_k<EPI_SILU, false><<<gN64, blk, 0, stream>>>(B0, Wb_t_down, XTE, 50000, 64, 512,
      NUL9, 1.0f, TAIL4);
  trip_r_k<<<12500, blk, 0, stream>>>(XTE, sph3, rbfW3, id3_ba, RT);
  gemm_k<EPI_NONE, false, true><<<gBil, blk, 0, stream>>>((const float*)RT, Wb_t_bil, XTB,
      50000, 64, 1024, NUL9, 1.0f, TAIL4);

  // ---- merge: x = (x_ca + x4 + x3)/sqrt3, up-projections accumulate in epilogue ----
  gemm_k<EPI_SILU, false><<<gFull, blk, 0, stream>>>(m, Wb_dense, B0, 50000, 512, 512,
      NUL9, INV_SQRT3f, TAIL4);
  gemm_k<EPI_ACC, false><<<gFull, blk, 0, stream>>>(XQB, Wb_q_up_ca, B0, 50000, 512, 32,
      nullptr, nullptr, nullptr, nullptr, s23, TAIL4);
  gemm_k<EPI_ACC, false><<<gFull, blk, 0, stream>>>(XQB, Wb_q_up_ac, B0, 50000, 512, 32,
      nullptr, INV, nullptr, nullptr, s23, TAIL4);
  gemm_k<EPI_ACC, false><<<gFull, blk, 0, stream>>>(XTB, Wb_t_up_ca, B0, 50000, 512, 64,
      nullptr, nullptr, nullptr, nullptr, s23, TAIL4);
  gemm_k<EPI_ACC, false><<<gFull, blk, 0, stream>>>(XTB, Wb_t_up_ac, B0, 50000, 512, 64,
      nullptr, INV, nullptr, nullptr, s23, TAIL4);

  // XTB (incl. Z5 region) now dead -> convert before/after weights into Z5
  wconv_k<<<dim3(8, 8, n2), blk, 0, stream>>>(b2);

  // ---- W_before (1 layer) + m add -> X := out_m; then W_after (2 layers, in place) ----
  gemm_k<EPI_SILU, false><<<gFull, blk, 0, stream>>>(B0, Wb_before0, B1, 50000, 512, 512,
      NUL9, 1.0f, TAIL4);
  gemm_k<EPI_RES2, false><<<gFull, blk, 0, stream>>>(B1, Wb_before1, out_m, 50000, 512, 512,
      nullptr, nullptr, m, B0, 1.0f, TAIL4);
  gemm_k<EPI_SILU, false><<<gFull, blk, 0, stream>>>(out_m, Wb_after[0], B1, 50000, 512, 512,
      NUL9, 1.0f, TAIL4);
  gemm_k<EPI_RES, false><<<gFull, blk, 0, stream>>>(B1, Wb_after[1], out_m, 50000, 512, 512,
      nullptr, nullptr, out_m, nullptr, INV_SQRT2f, TAIL4);
  gemm_k<EPI_SILU, false><<<gFull, blk, 0, stream>>>(out_m, Wb_after[2], B1, 50000, 512, 512,
      NUL9, 1.0f, TAIL4);
  gemm_k<EPI_RES, false><<<gFull, blk, 0, stream>>>(B1, Wb_after[3], out_m, 50000, 512, 512,
      nullptr, nullptr, out_m, nullptr, INV_SQRT2f, TAIL4);
  // out_m = m_after

  // ---- atom update ----
  rbf_proj_k<<<100000, blk, 0, stream>>>(rbf_h, W_au_rbf, B1, 50000);
  zero_k<<<10000, blk, 0, stream>>>(A0, 2560000);
  atom_scatter_k<<<100000, blk, 0, stream>>>(out_m, B1, idx_t, A0, 50000);
  gemm_k<EPI_SILU, false><<<gAtom, blk, 0, stream>>>(A0, Wb_au_dns, A1, 5000, 128, 512,
      NUL9, 1.0f, TAIL4);
  for (int l = 0; l < 3; ++l) {
    gemm_k<EPI_SILU, false><<<gAtom, blk, 0, stream>>>(A1, Wb_au_res[2 * l],
        A2, 5000, 128, 128, NUL9, 1.0f, TAIL4);
    gemm_k<EPI_RES, false><<<gAtom, blk, 0, stream>>>(A2, Wb_au_res[2 * l + 1],
        A1, 5000, 128, 128, nullptr, nullptr, A1, nullptr, INV_SQRT2f, TAIL4);
  }
  hout_k<<<2500, blk, 0, stream>>>(h, A1, out_h, 640000);

  // A0 region dead -> convert concat/resm weights into Z3
  wconv_k<<<dim3(12, 8, n3), blk, 0, stream>>>(b3);   // max K=768 (concat)

  // ---- concat re-embedding + W_resm, final m write (in place on out_m) ----
  gemm_k<EPI_SILU, true><<<gFull, blk, 0, stream>>>(nullptr, Wb_concat, B0, 50000, 512, 768,
      nullptr, nullptr, nullptr, nullptr, 1.0f, out_h, idx_s, idx_t, out_m);
  gemm_k<EPI_SILU, false><<<gFull, blk, 0, stream>>>(B0, Wb_resm0, B1, 50000, 512, 512,
      NUL9, 1.0f, TAIL4);
  gemm_k<EPI_RES2, false><<<gFull, blk, 0, stream>>>(B1, Wb_resm1, out_m, 50000, 512, 512,
      nullptr, nullptr, out_m, B0, 1.0f, TAIL4);
#undef NUL9
#undef TAIL4
}